// Round 3
// baseline (266.189 us; speedup 1.0000x reference)
//
#include <hip/hip_runtime.h>
#include <hip/hip_bf16.h>
#include <stdint.h>

// ---- problem constants ----
#define B_  4
#define T_  2048
#define D_  1024
#define H_  16
#define HD_ 64

typedef short s16x8 __attribute__((ext_vector_type(8)));
typedef short s16x4 __attribute__((ext_vector_type(4)));
typedef float f32x4 __attribute__((ext_vector_type(4)));

#define MFMA32(a, b, c) __builtin_amdgcn_mfma_f32_16x16x32_bf16(a, b, c, 0, 0, 0)

// raw v_exp_f32 (2^x) without OCML denormal-handling wrapper
#if __has_builtin(__builtin_amdgcn_exp2f)
#define FEXP2(x) __builtin_amdgcn_exp2f(x)
#else
#define FEXP2(x) exp2f(x)
#endif

__device__ __forceinline__ unsigned short f2bf(float f) {
    union { float f; unsigned int u; } v; v.f = f;
    unsigned int r = v.u + 0x7fffu + ((v.u >> 16) & 1u);   // RNE
    return (unsigned short)(r >> 16);
}

__device__ __forceinline__ unsigned int pkbf(float a, float b) {
    __hip_bfloat162 h = __float22bfloat162_rn(float2{a, b});  // v_cvt_pk_bf16_f32
    union { __hip_bfloat162 h; unsigned int u; } v; v.h = h;
    return v.u;
}

__device__ __forceinline__ void async16(const void* g, void* l) {
    __builtin_amdgcn_global_load_lds(
        (const __attribute__((address_space(1))) unsigned int*)g,
        (__attribute__((address_space(3))) unsigned int*)l, 16, 0, 0);
}

// -------- fused prep: cast x -> bf16  +  transpose-cast both weights -----
// blocks [0, 8192):        cast x (4 elems/thread)
// blocks [8192, 11264):    W_qkv [1024,3072] -> Wqt [3072,1024]
// blocks [11264, 12288):   W_out [1024,1024] -> Wot [1024,1024]
__global__ __launch_bounds__(256)
void prep_kernel(const float* __restrict__ x, unsigned short* __restrict__ xb,
                 const float* __restrict__ Wq, unsigned short* __restrict__ Wqt,
                 const float* __restrict__ Wo, unsigned short* __restrict__ Wot) {
    const int blk = blockIdx.x;
    const int tid = threadIdx.x;
    if (blk < 8192) {
        const int i = blk * 256 + tid;          // n4 = 2097152
        float4 v = ((const float4*)x)[i];
        ushort4 o;
        o.x = f2bf(v.x); o.y = f2bf(v.y); o.z = f2bf(v.z); o.w = f2bf(v.w);
        ((ushort4*)xb)[i] = o;
        return;
    }
    __shared__ float t[32][33];
    const float* W; unsigned short* Wt; int K, N, bx, by;
    if (blk < 11264) {
        const int idx = blk - 8192;             // 96 x 32
        W = Wq; Wt = Wqt; K = 1024; N = 3072;
        bx = (idx % 96) * 32; by = (idx / 96) * 32;
    } else {
        const int idx = blk - 11264;            // 32 x 32
        W = Wo; Wt = Wot; K = 1024; N = 1024;
        bx = (idx % 32) * 32; by = (idx / 32) * 32;
    }
    const int tx = tid & 31, ty = tid >> 5;
    #pragma unroll
    for (int j = 0; j < 32; j += 8)
        t[ty + j][tx] = W[(size_t)(by + ty + j) * N + bx + tx];
    __syncthreads();
    #pragma unroll
    for (int j = 0; j < 32; j += 8)
        Wt[(size_t)(bx + ty + j) * K + by + tx] = f2bf(t[tx][ty + j]);
}

// ---------------- bf16 MFMA GEMM: C = A[M,K] @ Bt[N,K]^T + bias --------
// 128^2 tile, BK=64, double-buffered, one barrier per K-iter.  Used for
// MODE 0 (projection GEMM, N=1024 -> 512 blocks = 2/CU, good balance).
template <int MODE>
__global__ __launch_bounds__(256)
void gemm_bt_kernel(const unsigned short* __restrict__ A,
                    const unsigned short* __restrict__ Bt,
                    const float* __restrict__ bias,
                    float* __restrict__ Cf,
                    unsigned short* __restrict__ Qo,
                    unsigned short* __restrict__ Ko,
                    unsigned short* __restrict__ Vo,
                    int M, int N, int K) {
    __shared__ __align__(16) unsigned short SMEM[4 * 128 * 64];  // 64 KB
    const int tid = threadIdx.x;
    const int w = tid >> 6, lane = tid & 63;
    const int laneN = lane & 15, quad = lane >> 4;
    const int rm0 = blockIdx.x * 128;      // m block (x fastest -> XCD stripe)
    const int rn0 = blockIdx.y * 128;      // n block
    const int wr = (w >> 1) * 64, wc = (w & 1) * 64;

    f32x4 acc[4][4] = {};

    auto issueG = [&](int kk, int bufsel) {
        unsigned short* As = SMEM + bufsel * 8192;
        unsigned short* Bs = SMEM + 16384 + bufsel * 8192;
        #pragma unroll
        for (int i = 0; i < 4; ++i) {
            const int c = i * 256 + tid;           // 0..1023 chunk id
            const int row = c >> 3, s = c & 7, g = s ^ (row & 7);
            async16(A + (size_t)(rm0 + row) * K + kk + g * 8,
                    (char*)As + (size_t)c * 16);
        }
        #pragma unroll
        for (int i = 0; i < 4; ++i) {
            const int c = i * 256 + tid;
            const int row = c >> 3, s = c & 7, g = s ^ (row & 7);
            async16(Bt + (size_t)(rn0 + row) * K + kk + g * 8,
                    (char*)Bs + (size_t)c * 16);
        }
    };

    issueG(0, 0);
    const int KI = K >> 6;                 // 16 iters at K=1024
    for (int it = 0; it < KI; ++it) {
        const int buf = it & 1;
        __syncthreads();                   // tile it ready; buf^1 reads done
        const unsigned short* As = SMEM + buf * 8192;
        const unsigned short* Bs = SMEM + 16384 + buf * 8192;
        s16x8 av[2][4], bv[2][4];
        #pragma unroll
        for (int h = 0; h < 2; ++h) {
            #pragma unroll
            for (int ms = 0; ms < 4; ++ms) {
                const int row = wr + ms * 16 + laneN;
                av[h][ms] = *(const s16x8*)&As[row * 64 + ((h * 4 + quad) ^ (row & 7)) * 8];
            }
            #pragma unroll
            for (int ns = 0; ns < 4; ++ns) {
                const int row = wc + ns * 16 + laneN;
                bv[h][ns] = *(const s16x8*)&Bs[row * 64 + ((h * 4 + quad) ^ (row & 7)) * 8];
            }
        }
        if (it + 1 < KI) issueG((it + 1) << 6, buf ^ 1);  // overlap w/ MFMA
        #pragma unroll
        for (int ms = 0; ms < 4; ++ms)
            #pragma unroll
            for (int ns = 0; ns < 4; ++ns) {
                acc[ms][ns] = MFMA32(av[0][ms], bv[0][ns], acc[ms][ns]);
                acc[ms][ns] = MFMA32(av[1][ms], bv[1][ns], acc[ms][ns]);
            }
    }

    if (MODE == 0) {
        #pragma unroll
        for (int ms = 0; ms < 4; ++ms) {
            const int gm0 = rm0 + wr + ms * 16 + quad * 4;
            #pragma unroll
            for (int ns = 0; ns < 4; ++ns) {
                const int gn = rn0 + wc + ns * 16 + laneN;
                const float bb = bias[gn];
                #pragma unroll
                for (int r = 0; r < 4; ++r)
                    Cf[(size_t)(gm0 + r) * N + gn] = acc[ms][ns][r] + bb;
            }
        }
    }
}

// -------- 256x128 8-wave triple-buffered counted-vmcnt QKV GEMM ----------
// BM=256, BN=128, BK=64: grid 32x24 = 768 blocks = EXACTLY 3 rounds of 256
// CUs (zero tail quantization; round-2's 384-block version wasted 25%).
// TRIPLE-buffered 144 KiB LDS -> each tile's 6 loads/thread get TWO full
// 8-wave x 32-MFMA iterations (~1200+ cyc) to land, covering L3/HBM latency
// (round-2's 2-deep buffer gave only ~600 cyc -> stalled every iteration).
// Raw s_barrier + steady-state s_waitcnt vmcnt(12): 2 tiles in flight
// across barriers, never drained to 0 in the main loop (T3+T4); setprio(1)
// around each 16-MFMA cluster (T5).  XOR swizzle chunk^(row&7) (0-conflict).
__global__ __launch_bounds__(512, 2)
void gemm256x128_qkv_kernel(const unsigned short* __restrict__ A,
                            const unsigned short* __restrict__ Bt,
                            const float* __restrict__ bias,
                            unsigned short* __restrict__ Qo,
                            unsigned short* __restrict__ Ko,
                            unsigned short* __restrict__ Vo,
                            int M, int N, int K) {
    __shared__ __align__(16) unsigned short SMEM[3 * 24576];   // 144 KiB
    const int tid = threadIdx.x;
    const int w = tid >> 6, lane = tid & 63;
    const int laneN = lane & 15, quad = lane >> 4;
    const int wm = w >> 1, wn = w & 1;                     // 4m x 2n wave grid
    const int rm0 = blockIdx.x * 256;                      // m fastest
    const int rn0 = blockIdx.y * 128;

    f32x4 acc[4][4] = {};

    // one K-tile = A 256x64 + B 128x64; 6 async16/thread (4 A + 2 B)
    auto issueTile = [&](int t, int bufsel) {
        const int kk = t << 6;
        unsigned short* As = SMEM + bufsel * 24576;
        unsigned short* Bs = As + 16384;
        #pragma unroll
        for (int i = 0; i < 4; ++i) {
            const int c = i * 512 + tid;                   // 0..2047
            const int row = c >> 3, s = c & 7, g = s ^ (row & 7);
            async16(A + (size_t)(rm0 + row) * K + kk + g * 8,
                    (char*)As + (size_t)c * 16);
        }
        #pragma unroll
        for (int i = 0; i < 2; ++i) {
            const int c = i * 512 + tid;                   // 0..1023
            const int row = c >> 3, s = c & 7, g = s ^ (row & 7);
            async16(Bt + (size_t)(rn0 + row) * K + kk + g * 8,
                    (char*)Bs + (size_t)c * 16);
        }
    };

    issueTile(0, 0);
    issueTile(1, 1);
    issueTile(2, 2);
    asm volatile("s_waitcnt vmcnt(12)" ::: "memory");      // tile 0 landed
    __builtin_amdgcn_s_barrier();
    asm volatile("" ::: "memory");

    const int KI = K >> 6;                                 // 16
    int buf = 0;
    for (int kt = 0; kt < KI; ++kt) {
        const unsigned short* As = SMEM + buf * 24576;
        const unsigned short* Bs = As + 16384;
        #pragma unroll
        for (int kh = 0; kh < 2; ++kh) {
            s16x8 av[4], bv[4];
            #pragma unroll
            for (int ns = 0; ns < 4; ++ns) {
                const int row = wn * 64 + ns * 16 + laneN;
                bv[ns] = *(const s16x8*)&Bs[row * 64 + ((kh * 4 + quad) ^ (row & 7)) * 8];
            }
            #pragma unroll
            for (int ms = 0; ms < 4; ++ms) {
                const int row = wm * 64 + ms * 16 + laneN;
                av[ms] = *(const s16x8*)&As[row * 64 + ((kh * 4 + quad) ^ (row & 7)) * 8];
            }
            __builtin_amdgcn_s_setprio(1);
            #pragma unroll
            for (int ms = 0; ms < 4; ++ms)
                #pragma unroll
                for (int ns = 0; ns < 4; ++ns)
                    acc[ms][ns] = MFMA32(av[ms], bv[ns], acc[ms][ns]);
            __builtin_amdgcn_s_setprio(0);
        }
        if (kt + 1 < KI) {
            // barrier (a): all waves done reading buf -> safe to restage
            __builtin_amdgcn_s_barrier();
            asm volatile("" ::: "memory");
            if (kt + 3 < KI) {
                issueTile(kt + 3, buf);
                asm volatile("s_waitcnt vmcnt(12)" ::: "memory"); // kt+1 landed
            } else if (kt + 2 < KI) {
                asm volatile("s_waitcnt vmcnt(6)" ::: "memory");  // kt+1 landed
            } else {
                asm volatile("s_waitcnt vmcnt(0)" ::: "memory");  // last landed
            }
            // barrier (b): everyone's loads for tile kt+1 are in LDS
            __builtin_amdgcn_s_barrier();
            asm volatile("" ::: "memory");
        }
        buf = (buf == 2) ? 0 : buf + 1;
    }

    // ---------------- QKV scatter epilogue (s block-uniform) -------------
    const int s = rn0 >> 10;                 // 0=Q 1=K 2=V  (1024 % 128 == 0)
    const int bidx = rm0 >> 11, t0 = rm0 & (T_ - 1);
    if (s < 2) {
        const float fs = (s == 0) ? 0.125f * 1.44269504088896f : 1.0f;
        unsigned short* P = (s == 0) ? Qo : Ko;
        #pragma unroll
        for (int ms = 0; ms < 4; ++ms) {
            const int lm0 = wm * 64 + ms * 16 + quad * 4;
            #pragma unroll
            for (int ns = 0; ns < 4; ++ns) {
                const int gn = rn0 + wn * 64 + ns * 16 + laneN;
                const float bb = bias[gn];
                const int rr = gn & 1023, hh = rr >> 6, dd = rr & 63;
                const size_t base = ((size_t)(bidx * H_ + hh) * T_ + t0);
                #pragma unroll
                for (int r = 0; r < 4; ++r)
                    P[(base + lm0 + r) * HD_ + dd] =
                        f2bf((acc[ms][ns][r] + bb) * fs);
            }
        }
    } else {
        // V: acc -> swizzled LDS [n_local 128][m_local 256] -> coalesced 16B
        __syncthreads();                     // all K-loop LDS reads done
        #pragma unroll
        for (int ms = 0; ms < 4; ++ms) {
            const int lm0 = wm * 64 + ms * 16 + quad * 4;
            #pragma unroll
            for (int ns = 0; ns < 4; ++ns) {
                const int nl = wn * 64 + ns * 16 + laneN;      // 0..127
                const float bb = bias[rn0 + nl];
                const int sw = (nl & 7) << 3;
                #pragma unroll
                for (int r = 0; r < 4; ++r)
                    SMEM[nl * 256 + ((lm0 + r) ^ sw)] =
                        f2bf(acc[ms][ns][r] + bb);
            }
        }
        __syncthreads();
        const int nl = tid >> 2, part = tid & 3;     // nl 0..127
        const int hh = nl >> 6, d = nl & 63;
        const int hAbs = bidx * H_ + ((rn0 & 1023) >> 6) + hh;
        unsigned short* rowp = Vo + ((size_t)hAbs * HD_ + d) * T_ + t0;
        const int swz = nl & 7;
        // iterate LOGICAL groups; physical group varies per lane
        #pragma unroll
        for (int j = 0; j < 8; ++j) {
            const int mgl = part * 8 + j;                       // logical group
            const int pg = (mgl & 24) | ((mgl & 7) ^ swz);      // physical slot
            const s16x8 vv = *(const s16x8*)&SMEM[nl * 256 + pg * 8];
            *(s16x8*)(rowp + mgl * 8) = vv;
        }
    }
}

// ---------------- flash attention v6 (proven 64-key tiles) ----------------
// grid(B*H, T/256), 512 thr (8 waves), 32 q-rows/wave, 256 q-rows/block.
// All q-blocks of one head land on one XCD -> K/V stay L2-resident.
// 8 waves share each staged K/V tile.  Fixed-max base-2 softmax; mask bias
// enters as the MFMA ACCUMULATOR INIT; exp is raw v_exp_f32.  S^T computed
// with PERMUTED K-rows so its C-layout concatenates into the 16x16x32
// A-operand -> PV and row-sum (B=ones) run as MFMA32 straight from
// registers.  K/V double-buffered in LDS via global_load_lds, XOR-swizzled;
// one barrier/tile.
__global__ __launch_bounds__(512, 4)
void attn_kernel(const unsigned short* __restrict__ Q,
                 const unsigned short* __restrict__ Kb,
                 const unsigned short* __restrict__ VT,
                 const int* __restrict__ mask,
                 unsigned short* __restrict__ Out) {
    __shared__ __align__(16) unsigned short Ks[2][64 * 64];  // [key][d] swizzled
    __shared__ __align__(16) unsigned short Vs[2][64 * 64];  // [d][key] swizzled
    __shared__ float biasF[T_];                              // fp32 mask bias
    const int tid = threadIdx.x;
    const int lane = tid & 63;
    const int w = tid >> 6;                                  // 0..7
    const int laneN = lane & 15, quad = lane >> 4;
    const int x7 = laneN & 7;
    const int bh = blockIdx.x;
    const int b = bh >> 4, h = bh & 15;
    const int qbase = blockIdx.y * 256 + w * 32;

    for (int i = tid; i < T_; i += 512)
        biasF[i] = mask[b * T_ + i] ? 0.f : -1.0e9f;

    // Q B-operand frags (pre-scaled by 0.125*log2e in GEMM1 epilogue)
    s16x8 qf[2][2];
    #pragma unroll
    for (int qg = 0; qg < 2; ++qg) {
        const size_t qoff = ((size_t)bh * T_ + qbase + qg * 16 + laneN) * HD_ + quad * 8;
        qf[qg][0] = *(const s16x8*)&Q[qoff];
        qf[qg][1] = *(const s16x8*)&Q[qoff + 32];
    }

    s16x8 ones;
    #pragma unroll
    for (int j = 0; j < 8; ++j) ones[j] = (short)0x3F80;   // bf16 1.0

    const size_t kRow0 = (size_t)bh * T_ * HD_;
    const size_t vRow0 = (size_t)bh * HD_ * T_;

    // K swizzle f(row) = (row&3) | (((row>>3)&1)<<2); V swizzle f(d) = d&7
    // 512 threads -> exactly one K chunk + one V chunk per thread per tile.
    auto issueTile = [&](int kt, int bufsel) {
        const int kbase = kt * 64;
        {
            const int c = tid;                              // 512 K chunks
            const int row = c >> 3, s = c & 7;
            const int fk = (row & 3) | (((row >> 3) & 1) << 2);
            const int g = s ^ fk;
            async16(Kb + kRow0 + (size_t)(kbase + row) * HD_ + g * 8,
                    &Ks[bufsel][c * 8]);
        }
        {
            const int c = tid;                              // 512 V chunks
            const int d = c >> 3, s = c & 7, g = s ^ (d & 7);
            async16(VT + vRow0 + (size_t)d * T_ + kbase + g * 8,
                    &Vs[bufsel][c * 8]);
        }
    };

    issueTile(0, 0);

    f32x4 O[2][4] = {};        // [qg][nt]; lane: q=quad*4+r, d=nt*16+laneN
    f32x4 liacc[2] = {};       // [qg]; lane: q=quad*4+r (row-sums via MFMA)

    // permuted K rows: rowA(laneN) covers keys quad*8+r after MFMA
    const int rowA = ((laneN >> 2) << 3) + (laneN & 3);     // +4 -> twin half

    #pragma unroll 2
    for (int kt = 0; kt < T_ / 64; ++kt) {
        const int buf = kt & 1;
        const int kbase = kt * 64;
        __syncthreads();                       // buf ready; buf^1 free
        if (kt + 1 < T_ / 64) issueTile(kt + 1, buf ^ 1);

        s16x8 pf[2][2];        // [qg][g32] A-operand P frags (k=quad*8+j)
        #pragma unroll
        for (int g32 = 0; g32 < 2; ++g32) {
            // K frags at permuted rows; slot = chunk ^ x7 (2-way, free)
            const int ra = g32 * 32 + rowA;
            const s16x8 kA0 = *(const s16x8*)&Ks[buf][(ra * 8 + (quad ^ x7)) * 8];
            const s16x8 kA1 = *(const s16x8*)&Ks[buf][(ra * 8 + ((4 + quad) ^ x7)) * 8];
            const s16x8 kB0 = *(const s16x8*)&Ks[buf][((ra + 4) * 8 + (quad ^ x7)) * 8];
            const s16x8 kB1 = *(const s16x8*)&Ks[buf][((ra + 4) * 8 + ((4 + quad) ^ x7)) * 8];
            // bias for keys g32*32 + quad*8 + (0..7) -> MFMA acc init
            const f32x4 bA = *(const f32x4*)&biasF[kbase + g32 * 32 + quad * 8];
            const f32x4 bB = *(const f32x4*)&biasF[kbase + g32 * 32 + quad * 8 + 4];
            #pragma unroll
            for (int qg = 0; qg < 2; ++qg) {
                f32x4 Sa = bA, Sb = bB;        // bias as accumulator init
                Sa = MFMA32(kA0, qf[qg][0], Sa);
                Sa = MFMA32(kA1, qf[qg][1], Sa);
                Sb = MFMA32(kB0, qf[qg][0], Sb);
                Sb = MFMA32(kB1, qf[qg][1], Sb);
                // fixed-max softmax: P = exp2(S)  (raw v_exp_f32)
                #pragma unroll
                for (int r = 0; r < 4; ++r) {
                    Sa[r] = FEXP2(Sa[r]);
                    Sb[r] = FEXP2(Sb[r]);
                }
                union { s16x8 v; unsigned int u[4]; } pu;
                pu.u[0] = pkbf(Sa[0], Sa[1]);
                pu.u[1] = pkbf(Sa[2], Sa[3]);
                pu.u[2] = pkbf(Sb[0], Sb[1]);
                pu.u[3] = pkbf(Sb[2], Sb[3]);
                pf[qg][g32] = pu.v;
            }
        }

        // ---- O += P @ V ; li += P @ 1 (all MFMA32, P from registers) ----
        #pragma unroll
        for (int g32 = 0; g32 < 2; ++g32) {
            s16x8 vf[4];
            #pragma unroll
            for (int nt = 0; nt < 4; ++nt) {
                const int d = nt * 16 + laneN;
                vf[nt] = *(const s16x8*)&Vs[buf][(d * 8 + ((g32 * 4 + quad) ^ x7)) * 8];
            }
            #pragma unroll
            for (int qg = 0; qg < 2; ++qg) {
                #pragma unroll
                for (int nt = 0; nt < 4; ++nt)
                    O[qg][nt] = MFMA32(pf[qg][g32], vf[nt], O[qg][nt]);
                liacc[qg] = MFMA32(pf[qg][g32], ones, liacc[qg]);
            }
        }
    }

    // ---- epilogue: Out[b,t, h*64+d] bf16 ; li already in O's layout ----
    #pragma unroll
    for (int qg = 0; qg < 2; ++qg) {
        #pragma unroll
        for (int r = 0; r < 4; ++r) {
            const float inv = 1.0f / liacc[qg][r];
            const int tq = qbase + qg * 16 + quad * 4 + r;
            #pragma unroll
            for (int nt = 0; nt < 4; ++nt)
                Out[(size_t)(b * T_ + tq) * D_ + h * HD_ + nt * 16 + laneN] =
                    f2bf(O[qg][nt][r] * inv);
        }
    }
}

extern "C" void kernel_launch(void* const* d_in, const int* in_sizes, int n_in,
                              void* d_out, int out_size, void* d_ws, size_t ws_size,
                              hipStream_t stream) {
    const float* x     = (const float*)d_in[0];
    const int*   mask  = (const int*)d_in[1];
    const float* W_qkv = (const float*)d_in[2];
    const float* b_qkv = (const float*)d_in[3];
    const float* W_out = (const float*)d_in[4];
    const float* b_out = (const float*)d_in[5];
    float* out = (float*)d_out;

    unsigned short* ws = (unsigned short*)d_ws;
    const size_t NX = (size_t)B_ * T_ * D_;          // 8388608
    unsigned short* xb  = ws;                        // x bf16; reused for attn out
    unsigned short* Qb  = xb + NX;
    unsigned short* Kb  = Qb + NX;
    unsigned short* Vtb = Kb + NX;
    unsigned short* Wqt = Vtb + NX;                  // [3D, D]
    unsigned short* Wot = Wqt + (size_t)3 * D_ * D_; // [D, D]
    unsigned short* attn = xb;                       // alias: xb dead after GEMM1

    prep_kernel<<<12288, 256, 0, stream>>>(x, xb, W_qkv, Wqt, W_out, Wot);
    gemm256x128_qkv_kernel<<<dim3(B_ * T_ / 256, 3 * D_ / 128), 512, 0, stream>>>(
        xb, Wqt, b_qkv, Qb, Kb, Vtb, B_ * T_, 3 * D_, D_);
    attn_kernel<<<dim3(B_ * H_, T_ / 256), 512, 0, stream>>>(Qb, Kb, Vtb, mask, attn);
    gemm_bt_kernel<0><<<dim3(B_ * T_ / 128, D_ / 128), 256, 0, stream>>>(
        attn, Wot, b_out, out, nullptr, nullptr, nullptr, B_ * T_, D_, D_);
}

// Round 4
// 257.010 us; speedup vs baseline: 1.0357x; 1.0357x over previous
//
#include <hip/hip_runtime.h>
#include <hip/hip_bf16.h>
#include <stdint.h>

// ---- problem constants ----
#define B_  4
#define T_  2048
#define D_  1024
#define H_  16
#define HD_ 64

typedef short s16x8 __attribute__((ext_vector_type(8)));
typedef short s16x4 __attribute__((ext_vector_type(4)));
typedef float f32x4 __attribute__((ext_vector_type(4)));

#define MFMA32(a, b, c) __builtin_amdgcn_mfma_f32_16x16x32_bf16(a, b, c, 0, 0, 0)

// raw v_exp_f32 (2^x) without OCML denormal-handling wrapper
#if __has_builtin(__builtin_amdgcn_exp2f)
#define FEXP2(x) __builtin_amdgcn_exp2f(x)
#else
#define FEXP2(x) exp2f(x)
#endif

__device__ __forceinline__ unsigned short f2bf(float f) {
    union { float f; unsigned int u; } v; v.f = f;
    unsigned int r = v.u + 0x7fffu + ((v.u >> 16) & 1u);   // RNE
    return (unsigned short)(r >> 16);
}

__device__ __forceinline__ unsigned int pkbf(float a, float b) {
    __hip_bfloat162 h = __float22bfloat162_rn(float2{a, b});  // v_cvt_pk_bf16_f32
    union { __hip_bfloat162 h; unsigned int u; } v; v.h = h;
    return v.u;
}

__device__ __forceinline__ void async16(const void* g, void* l) {
    __builtin_amdgcn_global_load_lds(
        (const __attribute__((address_space(1))) unsigned int*)g,
        (__attribute__((address_space(3))) unsigned int*)l, 16, 0, 0);
}

// -------- fused prep: cast x -> bf16  +  transpose-cast both weights -----
// blocks [0, 8192):        cast x (4 elems/thread)
// blocks [8192, 11264):    W_qkv [1024,3072] -> Wqt [3072,1024]
// blocks [11264, 12288):   W_out [1024,1024] -> Wot [1024,1024]
__global__ __launch_bounds__(256)
void prep_kernel(const float* __restrict__ x, unsigned short* __restrict__ xb,
                 const float* __restrict__ Wq, unsigned short* __restrict__ Wqt,
                 const float* __restrict__ Wo, unsigned short* __restrict__ Wot) {
    const int blk = blockIdx.x;
    const int tid = threadIdx.x;
    if (blk < 8192) {
        const int i = blk * 256 + tid;          // n4 = 2097152
        float4 v = ((const float4*)x)[i];
        ushort4 o;
        o.x = f2bf(v.x); o.y = f2bf(v.y); o.z = f2bf(v.z); o.w = f2bf(v.w);
        ((ushort4*)xb)[i] = o;
        return;
    }
    __shared__ float t[32][33];
    const float* W; unsigned short* Wt; int K, N, bx, by;
    if (blk < 11264) {
        const int idx = blk - 8192;             // 96 x 32
        W = Wq; Wt = Wqt; K = 1024; N = 3072;
        bx = (idx % 96) * 32; by = (idx / 96) * 32;
    } else {
        const int idx = blk - 11264;            // 32 x 32
        W = Wo; Wt = Wot; K = 1024; N = 1024;
        bx = (idx % 32) * 32; by = (idx / 32) * 32;
    }
    const int tx = tid & 31, ty = tid >> 5;
    #pragma unroll
    for (int j = 0; j < 32; j += 8)
        t[ty + j][tx] = W[(size_t)(by + ty + j) * N + bx + tx];
    __syncthreads();
    #pragma unroll
    for (int j = 0; j < 32; j += 8)
        Wt[(size_t)(bx + ty + j) * K + by + tx] = f2bf(t[tx][ty + j]);
}

// ---------------- bf16 MFMA GEMM: C = A[M,K] @ Bt[N,K]^T + bias --------
// BK=64, DOUBLE-BUFFERED 64 KB LDS, ONE barrier per K-iter: prefetch of
// tile k+1 issues before the MFMA burst of tile k, so the global->LDS
// latency overlaps compute and the barrier's vmcnt drain is pre-hidden.
// XOR-swizzled LDS (slot = chunk ^ (row&7)); grid(m-blocks, n-blocks) so
// linear id is m-fastest -> each XCD owns an L2-resident A row-stripe.
// MODE 0: Cf = acc + bias (fp32). MODE 1: QKV scatter (s block-uniform);
// Q pre-scaled by 0.125*log2e; V written via LDS transpose, coalesced 16B.
// [PROVEN 247 us baseline config — rounds 2/3's 256-tile counted-vmcnt
// variants measured +17 us; reverted.]
template <int MODE>
__global__ __launch_bounds__(256)
void gemm_bt_kernel(const unsigned short* __restrict__ A,
                    const unsigned short* __restrict__ Bt,
                    const float* __restrict__ bias,
                    float* __restrict__ Cf,
                    unsigned short* __restrict__ Qo,
                    unsigned short* __restrict__ Ko,
                    unsigned short* __restrict__ Vo,
                    int M, int N, int K) {
    __shared__ __align__(16) unsigned short SMEM[4 * 128 * 64];  // 64 KB
    const int tid = threadIdx.x;
    const int w = tid >> 6, lane = tid & 63;
    const int laneN = lane & 15, quad = lane >> 4;
    const int rm0 = blockIdx.x * 128;      // m block (x fastest -> XCD stripe)
    const int rn0 = blockIdx.y * 128;      // n block
    const int wr = (w >> 1) * 64, wc = (w & 1) * 64;

    f32x4 acc[4][4] = {};

    auto issueG = [&](int kk, int bufsel) {
        unsigned short* As = SMEM + bufsel * 8192;
        unsigned short* Bs = SMEM + 16384 + bufsel * 8192;
        #pragma unroll
        for (int i = 0; i < 4; ++i) {
            const int c = i * 256 + tid;           // 0..1023 chunk id
            const int row = c >> 3, s = c & 7, g = s ^ (row & 7);
            async16(A + (size_t)(rm0 + row) * K + kk + g * 8,
                    (char*)As + (size_t)c * 16);
        }
        #pragma unroll
        for (int i = 0; i < 4; ++i) {
            const int c = i * 256 + tid;
            const int row = c >> 3, s = c & 7, g = s ^ (row & 7);
            async16(Bt + (size_t)(rn0 + row) * K + kk + g * 8,
                    (char*)Bs + (size_t)c * 16);
        }
    };

    issueG(0, 0);
    const int KI = K >> 6;                 // 16 iters at K=1024
    for (int it = 0; it < KI; ++it) {
        const int buf = it & 1;
        __syncthreads();                   // tile it ready; buf^1 reads done
        const unsigned short* As = SMEM + buf * 8192;
        const unsigned short* Bs = SMEM + 16384 + buf * 8192;
        s16x8 av[2][4], bv[2][4];
        #pragma unroll
        for (int h = 0; h < 2; ++h) {
            #pragma unroll
            for (int ms = 0; ms < 4; ++ms) {
                const int row = wr + ms * 16 + laneN;
                av[h][ms] = *(const s16x8*)&As[row * 64 + ((h * 4 + quad) ^ (row & 7)) * 8];
            }
            #pragma unroll
            for (int ns = 0; ns < 4; ++ns) {
                const int row = wc + ns * 16 + laneN;
                bv[h][ns] = *(const s16x8*)&Bs[row * 64 + ((h * 4 + quad) ^ (row & 7)) * 8];
            }
        }
        if (it + 1 < KI) issueG((it + 1) << 6, buf ^ 1);  // overlap w/ MFMA
        #pragma unroll
        for (int ms = 0; ms < 4; ++ms)
            #pragma unroll
            for (int ns = 0; ns < 4; ++ns) {
                acc[ms][ns] = MFMA32(av[0][ms], bv[0][ns], acc[ms][ns]);
                acc[ms][ns] = MFMA32(av[1][ms], bv[1][ns], acc[ms][ns]);
            }
    }

    if (MODE == 0) {
        #pragma unroll
        for (int ms = 0; ms < 4; ++ms) {
            const int gm0 = rm0 + wr + ms * 16 + quad * 4;
            #pragma unroll
            for (int ns = 0; ns < 4; ++ns) {
                const int gn = rn0 + wc + ns * 16 + laneN;
                const float bb = bias[gn];
                #pragma unroll
                for (int r = 0; r < 4; ++r)
                    Cf[(size_t)(gm0 + r) * N + gn] = acc[ms][ns][r] + bb;
            }
        }
    } else {
        const int s = rn0 >> 10;                 // 0=Q 1=K 2=V, block-uniform
        const int bidx = rm0 >> 11, t0 = rm0 & (T_ - 1);
        if (s < 2) {
            const float fs = (s == 0) ? 0.125f * 1.44269504088896f : 1.0f;
            unsigned short* P = (s == 0) ? Qo : Ko;
            #pragma unroll
            for (int ms = 0; ms < 4; ++ms) {
                const int lm0 = wr + ms * 16 + quad * 4;
                #pragma unroll
                for (int ns = 0; ns < 4; ++ns) {
                    const int gn = rn0 + wc + ns * 16 + laneN;
                    const float bb = bias[gn];
                    const int rr = gn & 1023, hh = rr >> 6, dd = rr & 63;
                    const size_t base = ((size_t)(bidx * H_ + hh) * T_ + t0);
                    #pragma unroll
                    for (int r = 0; r < 4; ++r)
                        P[(base + lm0 + r) * HD_ + dd] =
                            f2bf((acc[ms][ns][r] + bb) * fs);
                }
            }
        } else {
            // V: acc -> swizzled LDS [n_local][m_local] -> coalesced stores
            __syncthreads();                     // all K-loop LDS reads done
            #pragma unroll
            for (int ms = 0; ms < 4; ++ms) {
                const int lm0 = wr + ms * 16 + quad * 4;
                #pragma unroll
                for (int ns = 0; ns < 4; ++ns) {
                    const int nl = wc + ns * 16 + laneN;
                    const float bb = bias[rn0 + nl];
                    const int sw = (nl & 7) << 3;
                    #pragma unroll
                    for (int r = 0; r < 4; ++r)
                        SMEM[nl * 128 + ((lm0 + r) ^ sw)] =
                            f2bf(acc[ms][ns][r] + bb);
                }
            }
            __syncthreads();
            const int nl = tid >> 1, half = tid & 1;
            const int hh = nl >> 6, d = nl & 63;
            const int hAbs = bidx * H_ + ((rn0 & 1023) >> 6) + hh;
            unsigned short* rowp = Vo + ((size_t)hAbs * HD_ + d) * T_ + t0;
            const int swz = nl & 7;
            #pragma unroll
            for (int j = 0; j < 8; ++j) {
                const s16x8 vv = *(const s16x8*)&SMEM[nl * 128 + half * 64 + j * 8];
                const int mlog = half * 64 + ((j ^ swz) * 8);
                *(s16x8*)(rowp + mlog) = vv;
            }
        }
    }
}

// ---------------- flash attention v7: 128-q-row blocks ----------------
// grid(B*H, T/128), 512 thr (8 waves), 16 q-rows/wave, 128 q-rows/block.
// CHANGE vs v6 (attn was latency-bound: MfmaUtil 39 / VALUBusy 50 / Occ 34,
// grid 512 blocks = 2 blocks/CU = 16 waves/CU cap): halving the q-block
// doubles the grid to 1024 blocks -> 4 blocks/CU (40 KiB LDS each) ->
// 32 waves/CU, giving the per-wave serial chain (MFMA->exp->pack->MFMA)
// 2x the co-resident waves to hide under.  K/V staging per block is
// unchanged (L2-resident; HBM untouched).  All per-tile math identical,
// qg dimension collapsed to 1.
__global__ __launch_bounds__(512, 4)
void attn_kernel(const unsigned short* __restrict__ Q,
                 const unsigned short* __restrict__ Kb,
                 const unsigned short* __restrict__ VT,
                 const int* __restrict__ mask,
                 unsigned short* __restrict__ Out) {
    __shared__ __align__(16) unsigned short Ks[2][64 * 64];  // [key][d] swizzled
    __shared__ __align__(16) unsigned short Vs[2][64 * 64];  // [d][key] swizzled
    __shared__ float biasF[T_];                              // fp32 mask bias
    const int tid = threadIdx.x;
    const int lane = tid & 63;
    const int w = tid >> 6;                                  // 0..7
    const int laneN = lane & 15, quad = lane >> 4;
    const int x7 = laneN & 7;
    const int bh = blockIdx.x;
    const int b = bh >> 4, h = bh & 15;
    const int qbase = blockIdx.y * 128 + w * 16;

    for (int i = tid; i < T_; i += 512)
        biasF[i] = mask[b * T_ + i] ? 0.f : -1.0e9f;

    // Q B-operand frags (pre-scaled by 0.125*log2e in GEMM1 epilogue)
    s16x8 qf[2];
    {
        const size_t qoff = ((size_t)bh * T_ + qbase + laneN) * HD_ + quad * 8;
        qf[0] = *(const s16x8*)&Q[qoff];
        qf[1] = *(const s16x8*)&Q[qoff + 32];
    }

    s16x8 ones;
    #pragma unroll
    for (int j = 0; j < 8; ++j) ones[j] = (short)0x3F80;   // bf16 1.0

    const size_t kRow0 = (size_t)bh * T_ * HD_;
    const size_t vRow0 = (size_t)bh * HD_ * T_;

    // K swizzle f(row) = (row&3) | (((row>>3)&1)<<2); V swizzle f(d) = d&7
    // 512 threads -> exactly one K chunk + one V chunk per thread per tile.
    auto issueTile = [&](int kt, int bufsel) {
        const int kbase = kt * 64;
        {
            const int c = tid;                              // 512 K chunks
            const int row = c >> 3, s = c & 7;
            const int fk = (row & 3) | (((row >> 3) & 1) << 2);
            const int g = s ^ fk;
            async16(Kb + kRow0 + (size_t)(kbase + row) * HD_ + g * 8,
                    &Ks[bufsel][c * 8]);
        }
        {
            const int c = tid;                              // 512 V chunks
            const int d = c >> 3, s = c & 7, g = s ^ (d & 7);
            async16(VT + vRow0 + (size_t)d * T_ + kbase + g * 8,
                    &Vs[bufsel][c * 8]);
        }
    };

    issueTile(0, 0);

    f32x4 O[4] = {};           // [nt]; lane: q=quad*4+r, d=nt*16+laneN
    f32x4 liacc = {};          // lane: q=quad*4+r (row-sums via MFMA)

    // permuted K rows: rowA(laneN) covers keys quad*8+r after MFMA
    const int rowA = ((laneN >> 2) << 3) + (laneN & 3);     // +4 -> twin half

    #pragma unroll 2
    for (int kt = 0; kt < T_ / 64; ++kt) {
        const int buf = kt & 1;
        const int kbase = kt * 64;
        __syncthreads();                       // buf ready; buf^1 free
        if (kt + 1 < T_ / 64) issueTile(kt + 1, buf ^ 1);

        s16x8 pf[2];           // [g32] A-operand P frags (k=quad*8+j)
        #pragma unroll
        for (int g32 = 0; g32 < 2; ++g32) {
            // K frags at permuted rows; slot = chunk ^ x7 (2-way, free)
            const int ra = g32 * 32 + rowA;
            const s16x8 kA0 = *(const s16x8*)&Ks[buf][(ra * 8 + (quad ^ x7)) * 8];
            const s16x8 kA1 = *(const s16x8*)&Ks[buf][(ra * 8 + ((4 + quad) ^ x7)) * 8];
            const s16x8 kB0 = *(const s16x8*)&Ks[buf][((ra + 4) * 8 + (quad ^ x7)) * 8];
            const s16x8 kB1 = *(const s16x8*)&Ks[buf][((ra + 4) * 8 + ((4 + quad) ^ x7)) * 8];
            // bias for keys g32*32 + quad*8 + (0..7) -> MFMA acc init
            const f32x4 bA = *(const f32x4*)&biasF[kbase + g32 * 32 + quad * 8];
            const f32x4 bB = *(const f32x4*)&biasF[kbase + g32 * 32 + quad * 8 + 4];
            f32x4 Sa = bA, Sb = bB;            // bias as accumulator init
            Sa = MFMA32(kA0, qf[0], Sa);
            Sa = MFMA32(kA1, qf[1], Sa);
            Sb = MFMA32(kB0, qf[0], Sb);
            Sb = MFMA32(kB1, qf[1], Sb);
            // fixed-max softmax: P = exp2(S)  (raw v_exp_f32)
            #pragma unroll
            for (int r = 0; r < 4; ++r) {
                Sa[r] = FEXP2(Sa[r]);
                Sb[r] = FEXP2(Sb[r]);
            }
            union { s16x8 v; unsigned int u[4]; } pu;
            pu.u[0] = pkbf(Sa[0], Sa[1]);
            pu.u[1] = pkbf(Sa[2], Sa[3]);
            pu.u[2] = pkbf(Sb[0], Sb[1]);
            pu.u[3] = pkbf(Sb[2], Sb[3]);
            pf[g32] = pu.v;
        }

        // ---- O += P @ V ; li += P @ 1 (all MFMA32, P from registers) ----
        #pragma unroll
        for (int g32 = 0; g32 < 2; ++g32) {
            s16x8 vf[4];
            #pragma unroll
            for (int nt = 0; nt < 4; ++nt) {
                const int d = nt * 16 + laneN;
                vf[nt] = *(const s16x8*)&Vs[buf][(d * 8 + ((g32 * 4 + quad) ^ x7)) * 8];
            }
            #pragma unroll
            for (int nt = 0; nt < 4; ++nt)
                O[nt] = MFMA32(pf[g32], vf[nt], O[nt]);
            liacc = MFMA32(pf[g32], ones, liacc);
        }
    }

    // ---- epilogue: Out[b,t, h*64+d] bf16 ; li already in O's layout ----
    #pragma unroll
    for (int r = 0; r < 4; ++r) {
        const float inv = 1.0f / liacc[r];
        const int tq = qbase + quad * 4 + r;
        #pragma unroll
        for (int nt = 0; nt < 4; ++nt)
            Out[(size_t)(b * T_ + tq) * D_ + h * HD_ + nt * 16 + laneN] =
                f2bf(O[nt][r] * inv);
    }
}

extern "C" void kernel_launch(void* const* d_in, const int* in_sizes, int n_in,
                              void* d_out, int out_size, void* d_ws, size_t ws_size,
                              hipStream_t stream) {
    const float* x     = (const float*)d_in[0];
    const int*   mask  = (const int*)d_in[1];
    const float* W_qkv = (const float*)d_in[2];
    const float* b_qkv = (const float*)d_in[3];
    const float* W_out = (const float*)d_in[4];
    const float* b_out = (const float*)d_in[5];
    float* out = (float*)d_out;

    unsigned short* ws = (unsigned short*)d_ws;
    const size_t NX = (size_t)B_ * T_ * D_;          // 8388608
    unsigned short* xb  = ws;                        // x bf16; reused for attn out
    unsigned short* Qb  = xb + NX;
    unsigned short* Kb  = Qb + NX;
    unsigned short* Vtb = Kb + NX;
    unsigned short* Wqt = Vtb + NX;                  // [3D, D]
    unsigned short* Wot = Wqt + (size_t)3 * D_ * D_; // [D, D]
    unsigned short* attn = xb;                       // alias: xb dead after GEMM1

    prep_kernel<<<12288, 256, 0, stream>>>(x, xb, W_qkv, Wqt, W_out, Wot);
    gemm_bt_kernel<1><<<dim3(B_ * T_ / 128, 3 * D_ / 128), 256, 0, stream>>>(
        xb, Wqt, b_qkv, nullptr, Qb, Kb, Vtb, B_ * T_, 3 * D_, D_);
    attn_kernel<<<dim3(B_ * H_, T_ / 128), 512, 0, stream>>>(Qb, Kb, Vtb, mask, attn);
    gemm_bt_kernel<0><<<dim3(B_ * T_ / 128, D_ / 128), 256, 0, stream>>>(
        attn, Wot, b_out, out, nullptr, nullptr, nullptr, B_ * T_, D_, D_);
}